// Round 7
// baseline (89.677 us; speedup 1.0000x reference)
//
#include <hip/hip_runtime.h>
#include <math.h>

// Geometry (fixed by setup_inputs):
//   carrier: (B=8, T=32768, 2*FD=258) float32, flat = 67,633,152 floats
//   x[b, s, f, c] -> flat = b*BSTRIDE + s*ROW + 2f + c
#define T_LEN   32768
#define ROW     258
#define BATCH   8
#define BSTRIDE (T_LEN * ROW)            // 8,454,144 floats per batch
#define NFLOAT  (BATCH * BSTRIDE)        // 67,633,152
#define N4      (NFLOAT / 4)             // 16,908,288 float4
#define NP      (N4 / 2)                 // 8,454,144 float4-pairs (32B units)
#define FIX_LIM (20 * ROW)               // 5160: fixup positions have (flat % BSTRIDE) < this

typedef float floatx4 __attribute__((ext_vector_type(4)));

__device__ __forceinline__ float apply_fix(float e, int j, int src,
                                           float bl, float omb) {
    const int s  = j / ROW;         // register index along T
    const int f2 = j - s * ROW;     // 2*freq + comp
    bool  fix = false;
    float sym = 0.0f;
    if (src == 0) {                               // START: regs<20, all freqs
        fix = (s < 20);
    } else if (src >= 1 && src <= 10) {           // DIGIT
        if (s >= 2 && s <= 11 && f2 < 2) {
            fix = true;
            sym = (s == 2 + (src - 1) % 10 && f2 == 0) ? 1.0f : 0.0f;
        }
    } else if (src == 11 || src == 12) {          // PLUS / MINUS
        if (s == 1 && f2 < 2) {
            fix = true;
            sym = (f2 == 0) ? ((src == 11) ? 1.0f : -1.0f) : 0.0f;
        }
    } else if (src == 13) {                       // EQUALS
        if (((s >= 14 && s <= 16) || s == 1 || (s >= 2 && s <= 11)) && f2 < 2)
            fix = true;                           // sym = 0
    }
    return fix ? (omb * e + bl * sym) : e;
}

// Round-5 structure (grid-stride + nt stores: 89us) widened to 32B/thread:
// two consecutive float4 loads in flight, then two nt stores. Contiguous
// 2KB per wave per step (NOT the round-3 failure's 8MB-strided bursts).
__global__ __launch_bounds__(256)
void arith_copy_blend(const floatx4* __restrict__ x4,
                      floatx4* __restrict__ o4,
                      const float* __restrict__ blend_p,
                      const int* __restrict__ src_p)
{
    const int stride = gridDim.x * blockDim.x;
    for (int p = blockIdx.x * blockDim.x + threadIdx.x; p < NP; p += stride) {
        const int i = 2 * p;
        floatx4 v0 = x4[i];
        floatx4 v1 = x4[i + 1];

        const unsigned flat = (unsigned)i << 2;            // first float index
        const unsigned b    = flat / (unsigned)BSTRIDE;    // magic-mul
        const int      rem  = (int)(flat - b * (unsigned)BSTRIDE);

        if (__builtin_expect(rem < FIX_LIM, 0)) {
            const int   src = *src_p;
            const float bl  = 1.0f / (1.0f + expf(-(*blend_p)));  // sigmoid
            const float omb = 1.0f - bl;
            #pragma unroll
            for (int k = 0; k < 4; ++k) v0[k] = apply_fix(v0[k], rem + k,     src, bl, omb);
            #pragma unroll
            for (int k = 0; k < 4; ++k) v1[k] = apply_fix(v1[k], rem + 4 + k, src, bl, omb);
        }
        __builtin_nontemporal_store(v0, &o4[i]);
        __builtin_nontemporal_store(v1, &o4[i + 1]);
    }
}

extern "C" void kernel_launch(void* const* d_in, const int* in_sizes, int n_in,
                              void* d_out, int out_size, void* d_ws, size_t ws_size,
                              hipStream_t stream) {
    const floatx4* x4      = (const floatx4*)d_in[0];  // carrier_freq_flat
    const float*   blend_p = (const float*)d_in[1];    // symbolic_blend (scalar)
    const int*     src_p   = (const int*)d_in[2];      // src_token
    // d_in[3] = tgt_token: only participates in the None-check, unused here.
    floatx4* o4 = (floatx4*)d_out;

    arith_copy_blend<<<2048, 256, 0, stream>>>(x4, o4, blend_p, src_p);
}